// Round 4
// baseline (2695.484 us; speedup 1.0000x reference)
//
#include <hip/hip_runtime.h>
#include <hip/hip_bf16.h>
#include <stdint.h>

#define B_   128
#define S_   512
#define C_   256
#define DG_  256

// d_out offsets (fp32 elements): outs, pi, sigma, mu, mask
#define OFF_PI   262144
#define OFF_SIG  917504
#define OFF_MU   3538944
#define OFF_MASK 6160384

typedef __hip_bfloat16 bf16;
typedef __bf16 bf16x8 __attribute__((ext_vector_type(8)));
typedef float  f32x4  __attribute__((ext_vector_type(4)));
typedef unsigned int u32;
typedef unsigned int u32x4 __attribute__((ext_vector_type(4)));

// ---- staging in device globals (zero d_ws dependence) ----
__device__ __align__(16) bf16  gWmain[768*256];   // Wih0[:, :256]
__device__ __align__(16) bf16  gWHH0 [768*256];
__device__ __align__(16) bf16  gWIH1 [768*256];
__device__ __align__(16) bf16  gWHH1 [768*256];
__device__ __align__(16) bf16  gWcat [96*512];    // [W_pi; W_sigma; W_mu; 0]
__device__ __align__(16) float gWtail[768*4];     // Wih0[:, 256:260] fp32
__device__ __align__(16) float gSm   [3200];      // small params fp32
__device__ __align__(16) bf16  gHbuf [B_*S_*DG_]; // h1 per (b,t), b-major (32 MB)
__device__ __align__(16) bf16  gH0   [B_*S_*DG_]; // h0 per (t,b), t-major (32 MB)
__device__ __align__(16) float gGi0  [50331648];  // gi0[t][b][768] fp32 (201 MB)
__device__ __align__(16) float gGi1  [50331648];  // gi1[t][b][768] fp32 (201 MB)
__device__ __align__(16) float gPn   [65536*4];   // prenet per (b,t)

// gSm offsets
#define SM_WPRE 0
#define SM_BPRE 16
#define SM_BIH0 20
#define SM_BHH0 788
#define SM_BIH1 1556
#define SM_BHH1 2324
#define SM_BPI  3092
#define SM_BSIG 3102
#define SM_BMU  3142

__device__ __forceinline__ bf16  f2b(float x){ return __float2bfloat16(x); }
__device__ __forceinline__ unsigned short b2u(bf16 x){
    union { bf16 b; unsigned short u; } c; c.b = x; return c.u;
}
__device__ __forceinline__ float sigm(float x){ return 1.f/(1.f + __expf(-x)); }
__device__ __forceinline__ float tanhfast(float x){ return 1.f - 2.f/(__expf(2.f*x) + 1.f); }
__device__ __forceinline__ f32x4 mfma16(bf16x8 a, bf16x8 b, f32x4 c){
    return __builtin_amdgcn_mfma_f32_16x16x32_bf16(a, b, c, 0, 0, 0);
}
__device__ __forceinline__ bf16x8 u2b(u32x4 x){
    union { u32x4 u; bf16x8 b; } c; c.u = x; return c.b;
}
__device__ __forceinline__ bf16x8 cvt8(const float* f){
    float4 a = *reinterpret_cast<const float4*>(f);
    float4 c = *reinterpret_cast<const float4*>(f + 4);
    bf16 o[8] = { f2b(a.x),f2b(a.y),f2b(a.z),f2b(a.w),
                  f2b(c.x),f2b(c.y),f2b(c.z),f2b(c.w) };
    return *reinterpret_cast<bf16x8*>(o);
}

// ---------------------------------------------------------------------------
// ingest: canonicalize fp32 params into device globals + prenet
#define IN_N0 199680
#define IN_N1 396288
#define IN_N2 592896
#define IN_N3 789504
#define IN_N4 838656
#define IN_N5 841838
#define IN_N6 1103982
__global__ __launch_bounds__(256) void k_ingest(
    const float* __restrict__ Wih0, const float* __restrict__ Whh0,
    const float* __restrict__ Wih1, const float* __restrict__ Whh1,
    const float* __restrict__ Wpi, const float* __restrict__ Wsig,
    const float* __restrict__ Wmu,
    const float* __restrict__ Wpre, const float* __restrict__ bpre,
    const float* __restrict__ bih0, const float* __restrict__ bhh0,
    const float* __restrict__ bih1, const float* __restrict__ bhh1,
    const float* __restrict__ bpi, const float* __restrict__ bsig,
    const float* __restrict__ bmu, const float* __restrict__ tgt)
{
    int j = blockIdx.x*256 + threadIdx.x;
    if (j < IN_N0){
        int r = j/260, c = j - r*260;
        float v = Wih0[j];
        if (c < 256) gWmain[r*256 + c] = f2b(v);
        else         gWtail[r*4 + (c-256)] = v;
    } else if (j < IN_N1){
        int k = j - IN_N0; gWHH0[k] = f2b(Whh0[k]);
    } else if (j < IN_N2){
        int k = j - IN_N1; gWIH1[k] = f2b(Wih1[k]);
    } else if (j < IN_N3){
        int k = j - IN_N2; gWHH1[k] = f2b(Whh1[k]);
    } else if (j < IN_N4){
        int k = j - IN_N3; int r = k >> 9, c = k & 511;
        float v = 0.f;
        if      (r < 10) v = Wpi[r*512 + c];
        else if (r < 50) v = Wsig[(r-10)*512 + c];
        else if (r < 90) v = Wmu[(r-50)*512 + c];
        gWcat[k] = f2b(v);
    } else if (j < IN_N5){
        int k = j - IN_N4;
        float v;
        if      (k < 16)   v = Wpre[k];
        else if (k < 20)   v = bpre[k-16];
        else if (k < 788)  v = bih0[k-20];
        else if (k < 1556) v = bhh0[k-788];
        else if (k < 2324) v = bih1[k-1556];
        else if (k < 3092) v = bhh1[k-2324];
        else if (k < 3102) v = bpi[k-3092];
        else if (k < 3142) v = bsig[k-3102];
        else               v = bmu[k-3142];
        gSm[k] = v;
    } else if (j < IN_N6){
        // prenet: pn[m][jj] = bpre[jj] + sum_q Wpre[jj][q]*tgt[m-1][q]  (m = b*512+t)
        int k = j - IN_N5, m = k>>2, jj = k&3, tq = m&511;
        float acc = bpre[jj];
        if (tq){
            const float* pv = tgt + (size_t)(m-1)*4;
            #pragma unroll
            for (int q=0;q<4;q++) acc += Wpre[jj*4+q]*pv[q];
        }
        gPn[m*4+jj] = acc;
    }
}

// ---------------------------------------------------------------------------
// k_gi0: gi0[t][b][n] = (Wih0 @ [enc;prenet])[n] + bih0[n] (+ bhh0[n] folded
// for the r/z gate halves, n<512 — pure-additive, so order-only fp change).
__global__ __launch_bounds__(256) void k_gi0(const float* __restrict__ enc)
{
    const int tid = threadIdx.x, w = tid>>6, lane = tid&63;
    const int col = lane&15, quad = lane>>4;
    const int m0 = blockIdx.x*64 + w*16;

    bf16x8 aF[8];
    #pragma unroll
    for (int kt=0; kt<8; kt++)
        aF[kt] = cvt8(enc + (size_t)(m0+col)*256 + kt*32 + quad*8);

    float4 pnr[4];
    #pragma unroll
    for (int r=0; r<4; r++)
        pnr[r] = *reinterpret_cast<const float4*>(gPn + (size_t)(m0 + quad*4 + r)*4);
    const int mrow = m0 + quad*4;

    for (int nt=0; nt<48; nt++){
        const int n = nt*16 + col;
        f32x4 acc = {0.f,0.f,0.f,0.f};
        #pragma unroll
        for (int kt=0; kt<8; kt++){
            bf16x8 bW = *reinterpret_cast<const bf16x8*>(gWmain + (size_t)n*256 + kt*32 + quad*8);
            acc = mfma16(aF[kt], bW, acc);
        }
        float4 wt = ((const float4*)gWtail)[n];
        float  bi = gSm[SM_BIH0 + n] + ((n < 512) ? gSm[SM_BHH0 + n] : 0.f);
        #pragma unroll
        for (int r=0; r<4; r++){
            int m = mrow + r; int bq = m>>9, tq = m&511;
            float v = acc[r] + bi + wt.x*pnr[r].x + wt.y*pnr[r].y
                              + wt.z*pnr[r].z + wt.w*pnr[r].w;
            gGi0[((size_t)tq*128 + bq)*768 + n] = v;
        }
    }
}

// ---------------------------------------------------------------------------
// k_gi1: gi1[t][b][n] = (Wih1 @ h0[t][b])[n] + bih1[n] (+ bhh1[n] for n<512).
__global__ __launch_bounds__(256) void k_gi1()
{
    const int tid = threadIdx.x, w = tid>>6, lane = tid&63;
    const int col = lane&15, quad = lane>>4;
    const int m0 = blockIdx.x*64 + w*16;

    bf16x8 aF[8];
    #pragma unroll
    for (int kt=0; kt<8; kt++)
        aF[kt] = *reinterpret_cast<const bf16x8*>(gH0 + (size_t)(m0+col)*256 + kt*32 + quad*8);

    for (int nt=0; nt<48; nt++){
        const int n = nt*16 + col;
        f32x4 acc = {0.f,0.f,0.f,0.f};
        #pragma unroll
        for (int kt=0; kt<8; kt++){
            bf16x8 bW = *reinterpret_cast<const bf16x8*>(gWIH1 + (size_t)n*256 + kt*32 + quad*8);
            acc = mfma16(aF[kt], bW, acc);
        }
        float bi = gSm[SM_BIH1 + n] + ((n < 512) ? gSm[SM_BHH1 + n] : 0.f);
        #pragma unroll
        for (int r=0; r<4; r++)
            gGi1[((size_t)(m0 + quad*4 + r))*768 + n] = acc[r] + bi;
    }
}

// ---------------------------------------------------------------------------
// k_rec: single-layer sequential ZoneOut-GRU. 32 blocks x 512 thr (8 waves),
// block = 4 batches, all dims local. Wave w owns q = {2w, 2w+1}: all 3 gates
// of those dim-slices -> gates fully in-register (no gA LDS, no gate barrier).
// 5 of 6 weight tiles pinned in AGPRs ("+a" keep-live; MFMA reads AGPR A
// natively), 1 tile in LDS (64 KB). h double-buffered in LDS -> ONE raw
// s_barrier per step with lgkmcnt-only wait (no vmcnt drain: gi loads and
// h stores float across the barrier).
__global__ __launch_bounds__(512, 2) void k_rec(int layer)
{
    __shared__ bf16 sW[8][8][64][8];   // 64 KB: per-wave streamed tile (g=2,q=2w+1)
    __shared__ bf16 hv[2][4][272];     // double-buffered h(t) bf16, stride 272 (2-way banks)

    const bf16*  __restrict__ W  = layer ? gWHH1 : gWHH0;
    const float* __restrict__ gi = layer ? gGi1  : gGi0;
    const int smOff = layer ? SM_BHH1 : SM_BHH0;
    bf16* __restrict__ hout = layer ? gHbuf : gH0;

    const int tid = threadIdx.x, w = tid>>6, lane = tid&63;
    const int col = lane&15, quad = lane>>4;
    const int bg4 = blockIdx.x*4;
    const int q0 = 2*w, q1 = 2*w+1;

    for (int i=tid; i<2*4*272; i+=512) (&hv[0][0][0])[i] = f2b(0.f);

    // ---- pinned tiles (AGPR): j=0..4 -> (g,q) = (0,q0),(1,q0),(2,q0),(0,q1),(1,q1)
    u32x4 wf[5][8];
    #pragma unroll
    for (int j=0;j<5;j++){
        const int g = (j<3) ? j : (j-3);
        const int q = (j<3) ? q0 : q1;
        const bf16* Wr = W + ((size_t)(g*256 + q*16 + col))*256;
        #pragma unroll
        for (int kt=0;kt<8;kt++){
            wf[j][kt] = *reinterpret_cast<const u32x4*>(Wr + kt*32 + quad*8);
            asm volatile("" : "+a"(wf[j][kt]));   // pin in AGPR, opaque: no remat
        }
    }
    // ---- LDS tile: (2, q1) ----
    {
        const bf16* Wr = W + ((size_t)(2*256 + q1*16 + col))*256;
        #pragma unroll
        for (int kt=0;kt<8;kt++)
            *reinterpret_cast<bf16x8*>(&sW[w][kt][lane][0]) =
                *reinterpret_cast<const bf16x8*>(Wr + kt*32 + quad*8);
    }

    // ---- per-lane gate setup: lanes with (col&4)==0 are gate-active ----
    const int b4 = col & 3;
    const int qm = (col & 8) ? q1 : q0;
    const int dq = qm*16 + quad*4;
    float4 bhn = *reinterpret_cast<const float4*>(&gSm[smOff + 512 + dq]);
    const float* gip = gi + (size_t)(bg4 + b4)*768 + dq;
    bf16* hop; size_t hstride;
    if (layer){ hop = hout + ((size_t)(bg4+b4)*512)*256 + dq; hstride = 256; }       // b-major
    else      { hop = hout + ((size_t)(bg4+b4))*256 + dq;     hstride = 128*256; }   // t-major
    float hreg[4] = {0.f,0.f,0.f,0.f};
    const bool act = (col & 4) == 0;

    __syncthreads();

    #pragma unroll 1
    for (int t=0; t<S_; t++){
        // gi(t) loads — latency hidden under the MFMA phase (no barrier drain)
        float4 gr4 = *reinterpret_cast<const float4*>(gip);
        float4 gz4 = *reinterpret_cast<const float4*>(gip + 256);
        float4 gn4 = *reinterpret_cast<const float4*>(gip + 512);

        const bf16* hrow = &hv[t&1][b4][0];
        f32x4 a0={0.f,0.f,0.f,0.f}, a1=a0, a2=a0, a3=a0, a4=a0, a5=a0;
        #pragma unroll
        for (int kt=0;kt<8;kt++){
            bf16x8 hb = *reinterpret_cast<const bf16x8*>(hrow + kt*32 + quad*8);
            bf16x8 s5 = *reinterpret_cast<const bf16x8*>(&sW[w][kt][lane][0]);
            a0 = mfma16(u2b(wf[0][kt]), hb, a0);
            a1 = mfma16(u2b(wf[1][kt]), hb, a1);
            a2 = mfma16(u2b(wf[2][kt]), hb, a2);
            a3 = mfma16(u2b(wf[3][kt]), hb, a3);
            a4 = mfma16(u2b(wf[4][kt]), hb, a4);
            a5 = mfma16(s5, hb, a5);
        }

        f32x4 ar = (col & 8) ? a3 : a0;
        f32x4 az = (col & 8) ? a4 : a1;
        f32x4 an = (col & 8) ? a5 : a2;
        if (act){
            float hp[4];
            #pragma unroll
            for (int r=0;r<4;r++){
                float rr = sigm(((const float*)&gr4)[r] + ar[r]);
                float zz = sigm(((const float*)&gz4)[r] + az[r]);
                float nn = tanhfast(((const float*)&gn4)[r] + rr*(an[r] + ((const float*)&bhn)[r]));
                float h  = hreg[r];
                float v  = 0.1f*h + 0.9f*((1.f-zz)*nn + zz*h);
                hreg[r] = v; hp[r] = v;
            }
            u32 lo = (u32)b2u(f2b(hp[0])) | ((u32)b2u(f2b(hp[1]))<<16);
            u32 hi = (u32)b2u(f2b(hp[2])) | ((u32)b2u(f2b(hp[3]))<<16);
            uint2 uu = make_uint2(lo, hi);
            *reinterpret_cast<uint2*>(&hv[(t&1)^1][b4][dq]) = uu;   // next-step buffer
            *reinterpret_cast<uint2*>(hop) = uu;                    // global H
        }
        hop += hstride;
        gip += 98304;   // 128*768

        // one barrier/step: LDS writes visible, NO vmcnt drain
        asm volatile("s_waitcnt lgkmcnt(0)" ::: "memory");
        __builtin_amdgcn_sched_barrier(0);
        __builtin_amdgcn_s_barrier();
        __builtin_amdgcn_sched_barrier(0);
    }
}

// ---------------------------------------------------------------------------
// Fused projection + heads: 512 blocks x 128 rows. [H|enc]@Wcat^T -> LDS ->
// softmax/elu/mu, fp32 stores.
__global__ __launch_bounds__(256) void k_proj(
    const float* __restrict__ enc, float* __restrict__ dout)
{
    __shared__ float st[128][100];
    const int tid = threadIdx.x, w = tid>>6, lane = tid&63;
    const int col = lane&15, quad = lane>>4;
    const int Mb = blockIdx.x*128;
    const int M0 = Mb + w*32;

    f32x4 acc[2][6];
    #pragma unroll
    for (int mt=0; mt<2; mt++)
        #pragma unroll
        for (int nt=0; nt<6; nt++) acc[mt][nt] = f32x4{0.f,0.f,0.f,0.f};

    #pragma unroll
    for (int kt=0; kt<16; kt++){
        bf16x8 a0, a1;
        if (kt < 8){
            a0 = *reinterpret_cast<const bf16x8*>(gHbuf + (size_t)(M0 +      col)*DG_ + kt*32 + quad*8);
            a1 = *reinterpret_cast<const bf16x8*>(gHbuf + (size_t)(M0 + 16 + col)*DG_ + kt*32 + quad*8);
        } else {
            a0 = cvt8(enc + (size_t)(M0 +      col)*C_ + (kt-8)*32 + quad*8);
            a1 = cvt8(enc + (size_t)(M0 + 16 + col)*C_ + (kt-8)*32 + quad*8);
        }
        #pragma unroll
        for (int nt=0; nt<6; nt++){
            bf16x8 b = *reinterpret_cast<const bf16x8*>(gWcat + (size_t)(nt*16 + col)*512 + kt*32 + quad*8);
            acc[0][nt] = mfma16(a0, b, acc[0][nt]);
            acc[1][nt] = mfma16(a1, b, acc[1][nt]);
        }
    }
    #pragma unroll
    for (int nt=0; nt<6; nt++)
        #pragma unroll
        for (int mt=0; mt<2; mt++)
            #pragma unroll
            for (int r=0; r<4; r++)
                st[w*32 + mt*16 + quad*4 + r][nt*16 + col] = acc[mt][nt][r];
    __syncthreads();

    if (tid < 128){
        const float* v = st[tid];
        const size_t m = (size_t)Mb + tid;
        float x[10], mx = -1e30f;
        #pragma unroll
        for (int g=0; g<10; g++){ x[g] = v[g] + gSm[SM_BPI+g]; mx = fmaxf(mx, x[g]); }
        float sum = 0.f;
        #pragma unroll
        for (int g=0; g<10; g++){ x[g] = __expf(x[g]-mx); sum += x[g]; }
        float inv = 1.f/sum;
        #pragma unroll
        for (int g=0; g<10; g++)
            dout[OFF_PI + m*10 + g] = x[g]*inv;
        #pragma unroll
        for (int i=0; i<40; i++){
            float s = v[10+i] + gSm[SM_BSIG+i];
            dout[OFF_SIG + m*40 + i] = (s > 0.f) ? (s + 1.f) : __expf(s);
        }
        #pragma unroll
        for (int i=0; i<40; i++)
            dout[OFF_MU + m*40 + i] = v[50+i] + gSm[SM_BMU+i];
    }
}

// ---------------------------------------------------------------------------
// blocks 0..255: outs = fp32 copy of tgt; blocks 256..383: mask
__global__ __launch_bounds__(256) void k_misc(const float* __restrict__ tgt,
    const int* __restrict__ dur, float* __restrict__ dout)
{
    if (blockIdx.x < 256){
        int i = blockIdx.x*256 + threadIdx.x;
        ((float4*)dout)[i] = ((const float4*)tgt)[i];
    } else {
        __shared__ int red[256];
        int b = blockIdx.x - 256;
        int c = 0;
        for (int s = threadIdx.x; s < S_; s += 256) c += (dur[b*S_ + s] > 0) ? 1 : 0;
        red[threadIdx.x] = c;
        __syncthreads();
        for (int off=128; off>0; off>>=1){
            if (threadIdx.x < off) red[threadIdx.x] += red[threadIdx.x+off];
            __syncthreads();
        }
        int snt = red[0];
        for (int s = threadIdx.x; s < S_; s += 256)
            dout[OFF_MASK + (size_t)b*S_ + s] = (s >= snt) ? 1.f : 0.f;
    }
}

// ---------------------------------------------------------------------------
extern "C" void kernel_launch(void* const* d_in, const int* in_sizes, int n_in,
                              void* d_out, int out_size, void* d_ws, size_t ws_size,
                              hipStream_t stream)
{
    (void)d_ws; (void)ws_size;
    const float* enc  = (const float*)d_in[0];
    const float* tgt  = (const float*)d_in[1];
    const int*   dur  = (const int*)  d_in[2];
    const float* Wpre = (const float*)d_in[3];
    const float* bpre = (const float*)d_in[4];
    const float* Wih0 = (const float*)d_in[5];
    const float* Whh0 = (const float*)d_in[6];
    const float* bih0 = (const float*)d_in[7];
    const float* bhh0 = (const float*)d_in[8];
    const float* Wih1 = (const float*)d_in[9];
    const float* Whh1 = (const float*)d_in[10];
    const float* bih1 = (const float*)d_in[11];
    const float* bhh1 = (const float*)d_in[12];
    const float* Wpi  = (const float*)d_in[13];
    const float* bpi  = (const float*)d_in[14];
    const float* Wsig = (const float*)d_in[15];
    const float* bsig = (const float*)d_in[16];
    const float* Wmu  = (const float*)d_in[17];
    const float* bmu  = (const float*)d_in[18];
    float* dout = (float*)d_out;

    hipLaunchKernelGGL(k_ingest, dim3(4313), dim3(256), 0, stream,
                       Wih0, Whh0, Wih1, Whh1, Wpi, Wsig, Wmu,
                       Wpre, bpre, bih0, bhh0, bih1, bhh1, bpi, bsig, bmu, tgt);
    hipLaunchKernelGGL(k_gi0,  dim3(1024), dim3(256), 0, stream, enc);
    hipLaunchKernelGGL(k_rec,  dim3(32),   dim3(512), 0, stream, 0);
    hipLaunchKernelGGL(k_gi1,  dim3(1024), dim3(256), 0, stream);
    hipLaunchKernelGGL(k_rec,  dim3(32),   dim3(512), 0, stream, 1);
    hipLaunchKernelGGL(k_proj, dim3(512),  dim3(256), 0, stream, enc, dout);
    hipLaunchKernelGGL(k_misc, dim3(384),  dim3(256), 0, stream, tgt, dur, dout);
}